// Round 4
// baseline (184.283 us; speedup 1.0000x reference)
//
#include <hip/hip_runtime.h>

#define IN_DIM   4096
#define OUT_DIM  4096
#define FAN_IN   64
#define ROWS     8                        // batch rows staged per block
#define NTHREADS 1024
#define O_PER_THREAD (OUT_DIM / NTHREADS) // 4 output columns per thread

// Bijective 16B-block swizzle: within each 8-col group, XOR low bits by group id.
// Spreads ds bank-start groups for both staging writes and gather reads.
__device__ __forceinline__ int bswz(int m) {
    return (m & ~7) | ((m ^ (m >> 3)) & 7);
}

// round-to-nearest-even-ish f32->bf16, packed pair (a=lo, b=hi)
__device__ __forceinline__ unsigned int pack_bf16(float a, float b) {
    unsigned int ua = __float_as_uint(a);
    ua += 0x7FFFu + ((ua >> 16) & 1u);
    unsigned int ub = __float_as_uint(b);
    ub += 0x7FFFu + ((ub >> 16) & 1u);
    return (ua >> 16) | (ub & 0xFFFF0000u);
}

// 1024 threads, 8 waves/SIMD target: VGPR cap 64 (current build: 52).
// LDS 64 KiB/block -> 2 blocks/CU -> 32 waves/CU (100% occupancy).
__global__ __launch_bounds__(NTHREADS, 8)
void ffi_sparse_kernel(const float* __restrict__ inp,
                       const float* __restrict__ W,
                       const int*   __restrict__ M,
                       const float* __restrict__ bias,
                       float* __restrict__ out)
{
    // [col][8 rows] as packed bf16 pairs: 4 uints (16 B) per column. 64 KiB.
    __shared__ unsigned int lds[IN_DIM * ROWS / 2];

    const int tid = threadIdx.x;
    const int r0  = blockIdx.x * ROWS;

    // ---------------- stage: 8 rows x 4096 cols, f32 -> bf16, transpose ----------------
    // Each iteration handles a 4x4 tile (4 rows x 4 cols = 16 elements).
    // Total tiles = ROWS*IN_DIM/16 = 2048 -> 2 iterations at 1024 threads.
    #pragma unroll
    for (int t = 0; t < (ROWS * IN_DIM / 16) / NTHREADS; ++t) {   // 2 iterations
        const int tile = tid + t * NTHREADS;     // 0..2047
        const int rblk = tile >> 10;             // 0..1 -> rows rblk*4 .. rblk*4+3
        const int c4   = (tile & 1023) << 2;     // column base 0..4092
        const float* src = inp + (size_t)(r0 + rblk * 4) * IN_DIM + c4;
        const float4 v0 = *(const float4*)(src);
        const float4 v1 = *(const float4*)(src + IN_DIM);
        const float4 v2 = *(const float4*)(src + 2 * IN_DIM);
        const float4 v3 = *(const float4*)(src + 3 * IN_DIM);

        unsigned int* p;
        p = lds + bswz(c4 + 0) * 4 + rblk * 2;
        *(uint2*)p = make_uint2(pack_bf16(v0.x, v1.x), pack_bf16(v2.x, v3.x));
        p = lds + bswz(c4 + 1) * 4 + rblk * 2;
        *(uint2*)p = make_uint2(pack_bf16(v0.y, v1.y), pack_bf16(v2.y, v3.y));
        p = lds + bswz(c4 + 2) * 4 + rblk * 2;
        *(uint2*)p = make_uint2(pack_bf16(v0.z, v1.z), pack_bf16(v2.z, v3.z));
        p = lds + bswz(c4 + 3) * 4 + rblk * 2;
        *(uint2*)p = make_uint2(pack_bf16(v0.w, v1.w), pack_bf16(v2.w, v3.w));
    }
    __syncthreads();

    // ---------------- gather + accumulate ----------------
    // One b128 per (output, k): 8 batch rows of column mask[o,k].
#define GSTEP(mi, wi) {                                                        \
        const int blk = bswz(mi);                                              \
        const uint4 d = *((const uint4*)lds + blk);                            \
        const float wv = (wi);                                                 \
        acc0 = fmaf(__uint_as_float(d.x << 16),          wv, acc0);            \
        acc1 = fmaf(__uint_as_float(d.x & 0xFFFF0000u),  wv, acc1);            \
        acc2 = fmaf(__uint_as_float(d.y << 16),          wv, acc2);            \
        acc3 = fmaf(__uint_as_float(d.y & 0xFFFF0000u),  wv, acc3);            \
        acc4 = fmaf(__uint_as_float(d.z << 16),          wv, acc4);            \
        acc5 = fmaf(__uint_as_float(d.z & 0xFFFF0000u),  wv, acc5);            \
        acc6 = fmaf(__uint_as_float(d.w << 16),          wv, acc6);            \
        acc7 = fmaf(__uint_as_float(d.w & 0xFFFF0000u),  wv, acc7);            \
    }

    // Cyclic output mapping: o = tid + i*NTHREADS -> consecutive lanes own
    // consecutive output columns -> fully coalesced 4B stores.
    #pragma unroll 1
    for (int i = 0; i < O_PER_THREAD; ++i) {
        const int o = tid + i * NTHREADS;
        const float bv = bias[o];
        float acc0 = bv, acc1 = bv, acc2 = bv, acc3 = bv;
        float acc4 = bv, acc5 = bv, acc6 = bv, acc7 = bv;

        const int*   mp = M + (size_t)o * FAN_IN;
        const float* wp = W + (size_t)o * FAN_IN;

        #pragma unroll 2
        for (int kk = 0; kk < FAN_IN; kk += 4) {
            const int4   m4 = *(const int4*)(mp + kk);
            const float4 w4 = *(const float4*)(wp + kk);
            GSTEP(m4.x, w4.x);
            GSTEP(m4.y, w4.y);
            GSTEP(m4.z, w4.z);
            GSTEP(m4.w, w4.w);
        }

        float* op = out + (size_t)r0 * OUT_DIM + o;
        op[0 * OUT_DIM] = acc0;
        op[1 * OUT_DIM] = acc1;
        op[2 * OUT_DIM] = acc2;
        op[3 * OUT_DIM] = acc3;
        op[4 * OUT_DIM] = acc4;
        op[5 * OUT_DIM] = acc5;
        op[6 * OUT_DIM] = acc6;
        op[7 * OUT_DIM] = acc7;
    }
#undef GSTEP
}

extern "C" void kernel_launch(void* const* d_in, const int* in_sizes, int n_in,
                              void* d_out, int out_size, void* d_ws, size_t ws_size,
                              hipStream_t stream) {
    const float* inp  = (const float*)d_in[0];
    const float* W    = (const float*)d_in[1];
    const int*   M    = (const int*)d_in[2];
    const float* bias = (const float*)d_in[3];
    float* out = (float*)d_out;

    const int n_rows = in_sizes[0] / IN_DIM;          // 4096
    dim3 grid(n_rows / ROWS), block(NTHREADS);
    ffi_sparse_kernel<<<grid, block, 0, stream>>>(inp, W, M, bias, out);
}

// Round 5
// 134.620 us; speedup vs baseline: 1.3689x; 1.3689x over previous
//
#include <hip/hip_runtime.h>

#define IN_DIM   4096
#define OUT_DIM  4096
#define FAN_IN   64
#define ROWS     8                        // batch rows staged per block
#define NTHREADS 512
#define O_PER_THREAD (OUT_DIM / NTHREADS) // 8 output columns per thread

// Bijective 16B-block swizzle: within each 8-col group, XOR low bits by group id.
__device__ __forceinline__ int bswz(int m) {
    return (m & ~7) | ((m ^ (m >> 3)) & 7);
}

// round-to-nearest-even-ish f32->bf16, packed pair (a=lo, b=hi)
__device__ __forceinline__ unsigned int pack_bf16(float a, float b) {
    unsigned int ua = __float_as_uint(a);
    ua += 0x7FFFu + ((ua >> 16) & 1u);
    unsigned int ub = __float_as_uint(b);
    ub += 0x7FFFu + ((ub >> 16) & 1u);
    return (ua >> 16) | (ub & 0xFFFF0000u);
}

// 512 threads, 64 KiB LDS -> 2 blocks/CU (LDS-capped) -> 16 waves/CU.
// min-waves=2 -> VGPR cap 256: spend registers on gather MLP (8-16 b128 in flight).
__global__ __launch_bounds__(NTHREADS, 2)
void ffi_sparse_kernel(const float* __restrict__ inp,
                       const float* __restrict__ W,
                       const int*   __restrict__ M,
                       const float* __restrict__ bias,
                       float* __restrict__ out)
{
    // [col][8 rows] as packed bf16 pairs: 4 uints (16 B) per column. 64 KiB.
    __shared__ unsigned int lds[IN_DIM * ROWS / 2];

    const int tid = threadIdx.x;
    const int r0  = blockIdx.x * ROWS;

    // ---------------- stage: 8 rows x 4096 cols, f32 -> bf16, transpose ----------------
    #pragma unroll
    for (int t = 0; t < (ROWS * IN_DIM / 16) / NTHREADS; ++t) {   // 4 iterations
        const int tile = tid + t * NTHREADS;     // 0..2047
        const int rblk = tile >> 10;             // 0..1
        const int c4   = (tile & 1023) << 2;     // column base
        const float* src = inp + (size_t)(r0 + rblk * 4) * IN_DIM + c4;
        const float4 v0 = *(const float4*)(src);
        const float4 v1 = *(const float4*)(src + IN_DIM);
        const float4 v2 = *(const float4*)(src + 2 * IN_DIM);
        const float4 v3 = *(const float4*)(src + 3 * IN_DIM);

        unsigned int* p;
        p = lds + bswz(c4 + 0) * 4 + rblk * 2;
        *(uint2*)p = make_uint2(pack_bf16(v0.x, v1.x), pack_bf16(v2.x, v3.x));
        p = lds + bswz(c4 + 1) * 4 + rblk * 2;
        *(uint2*)p = make_uint2(pack_bf16(v0.y, v1.y), pack_bf16(v2.y, v3.y));
        p = lds + bswz(c4 + 2) * 4 + rblk * 2;
        *(uint2*)p = make_uint2(pack_bf16(v0.z, v1.z), pack_bf16(v2.z, v3.z));
        p = lds + bswz(c4 + 3) * 4 + rblk * 2;
        *(uint2*)p = make_uint2(pack_bf16(v0.w, v1.w), pack_bf16(v2.w, v3.w));
    }
    __syncthreads();

    // ---------------- gather + accumulate ----------------
#define CONSUME(d, wv) {                                                       \
        acc0 = fmaf(__uint_as_float(d.x << 16),          wv, acc0);            \
        acc1 = fmaf(__uint_as_float(d.x & 0xFFFF0000u),  wv, acc1);            \
        acc2 = fmaf(__uint_as_float(d.y << 16),          wv, acc2);            \
        acc3 = fmaf(__uint_as_float(d.y & 0xFFFF0000u),  wv, acc3);            \
        acc4 = fmaf(__uint_as_float(d.z << 16),          wv, acc4);            \
        acc5 = fmaf(__uint_as_float(d.z & 0xFFFF0000u),  wv, acc5);            \
        acc6 = fmaf(__uint_as_float(d.w << 16),          wv, acc6);            \
        acc7 = fmaf(__uint_as_float(d.w & 0xFFFF0000u),  wv, acc7);            \
    }

    const uint4* __restrict__ ldsq = (const uint4*)lds;

    // Cyclic output mapping -> coalesced stores.
    #pragma unroll 1
    for (int i = 0; i < O_PER_THREAD; ++i) {
        const int o = tid + i * NTHREADS;
        const float bv = bias[o];
        float acc0 = bv, acc1 = bv, acc2 = bv, acc3 = bv;
        float acc4 = bv, acc5 = bv, acc6 = bv, acc7 = bv;

        const int*   mp = M + (size_t)o * FAN_IN;
        const float* wp = W + (size_t)o * FAN_IN;

        // Batch 8 gathers: 8 addresses -> 8 independent ds_read_b128 -> consume.
        // unroll 2 => up to 16 b128 in flight per wave.
        #pragma unroll 2
        for (int kk = 0; kk < FAN_IN; kk += 8) {
            const int4   m0 = *(const int4*)(mp + kk);
            const int4   m1 = *(const int4*)(mp + kk + 4);
            const float4 w0 = *(const float4*)(wp + kk);
            const float4 w1 = *(const float4*)(wp + kk + 4);

            const int a0 = bswz(m0.x), a1 = bswz(m0.y), a2 = bswz(m0.z), a3 = bswz(m0.w);
            const int a4 = bswz(m1.x), a5 = bswz(m1.y), a6 = bswz(m1.z), a7 = bswz(m1.w);

            const uint4 d0 = ldsq[a0];
            const uint4 d1 = ldsq[a1];
            const uint4 d2 = ldsq[a2];
            const uint4 d3 = ldsq[a3];
            const uint4 d4 = ldsq[a4];
            const uint4 d5 = ldsq[a5];
            const uint4 d6 = ldsq[a6];
            const uint4 d7 = ldsq[a7];

            CONSUME(d0, w0.x);
            CONSUME(d1, w0.y);
            CONSUME(d2, w0.z);
            CONSUME(d3, w0.w);
            CONSUME(d4, w1.x);
            CONSUME(d5, w1.y);
            CONSUME(d6, w1.z);
            CONSUME(d7, w1.w);
        }

        float* op = out + (size_t)r0 * OUT_DIM + o;
        op[0 * OUT_DIM] = acc0;
        op[1 * OUT_DIM] = acc1;
        op[2 * OUT_DIM] = acc2;
        op[3 * OUT_DIM] = acc3;
        op[4 * OUT_DIM] = acc4;
        op[5 * OUT_DIM] = acc5;
        op[6 * OUT_DIM] = acc6;
        op[7 * OUT_DIM] = acc7;
    }
#undef CONSUME
}

extern "C" void kernel_launch(void* const* d_in, const int* in_sizes, int n_in,
                              void* d_out, int out_size, void* d_ws, size_t ws_size,
                              hipStream_t stream) {
    const float* inp  = (const float*)d_in[0];
    const float* W    = (const float*)d_in[1];
    const int*   M    = (const int*)d_in[2];
    const float* bias = (const float*)d_in[3];
    float* out = (float*)d_out;

    const int n_rows = in_sizes[0] / IN_DIM;          // 4096
    dim3 grid(n_rows / ROWS), block(NTHREADS);
    ffi_sparse_kernel<<<grid, block, 0, stream>>>(inp, W, M, bias, out);
}

// Round 6
// 131.955 us; speedup vs baseline: 1.3966x; 1.0202x over previous
//
#include <hip/hip_runtime.h>

#define IN_DIM   4096
#define OUT_DIM  4096
#define FAN_IN   64
#define ROWS     8
#define NTHREADS 512
#define O_PER_THREAD (OUT_DIM / NTHREADS) // 8

// Bijective 16B-block swizzle: spreads LDS bank-start groups.
__device__ __forceinline__ int bswz(int m) {
    return (m & ~7) | ((m ^ (m >> 3)) & 7);
}

// round-to-nearest f32->bf16, packed pair (a=lo, b=hi)
__device__ __forceinline__ unsigned int pack_bf16(float a, float b) {
    unsigned int ua = __float_as_uint(a);
    ua += 0x7FFFu + ((ua >> 16) & 1u);
    unsigned int ub = __float_as_uint(b);
    ub += 0x7FFFu + ((ub >> 16) & 1u);
    return (ua >> 16) | (ub & 0xFFFF0000u);
}

// 64 KiB LDS -> 2 blocks/CU (LDS-capped, 16 waves). min-waves=4 -> VGPR cap 128:
// enough for the 3-stage pipeline (d-ring 32 + mw-ring 32 + acc 8 + misc).
__global__ __launch_bounds__(NTHREADS, 4)
void ffi_sparse_kernel(const float* __restrict__ inp,
                       const float* __restrict__ W,
                       const int*   __restrict__ M,
                       const float* __restrict__ bias,
                       float* __restrict__ out)
{
    // [col][8 rows] packed bf16 pairs: one uint4 (16 B) per column. 64 KiB.
    __shared__ unsigned int lds[IN_DIM * ROWS / 2];

    const int tid = threadIdx.x;
    const int r0  = blockIdx.x * ROWS;

    // ---------------- stage: 8 rows x 4096 cols, f32 -> bf16, transpose ----------------
    #pragma unroll
    for (int t = 0; t < (ROWS * IN_DIM / 16) / NTHREADS; ++t) {   // 4 iterations
        const int tile = tid + t * NTHREADS;     // 0..2047
        const int rblk = tile >> 10;             // 0..1
        const int c4   = (tile & 1023) << 2;     // column base
        const float* src = inp + (size_t)(r0 + rblk * 4) * IN_DIM + c4;
        const float4 v0 = *(const float4*)(src);
        const float4 v1 = *(const float4*)(src + IN_DIM);
        const float4 v2 = *(const float4*)(src + 2 * IN_DIM);
        const float4 v3 = *(const float4*)(src + 3 * IN_DIM);

        unsigned int* p;
        p = lds + bswz(c4 + 0) * 4 + rblk * 2;
        *(uint2*)p = make_uint2(pack_bf16(v0.x, v1.x), pack_bf16(v2.x, v3.x));
        p = lds + bswz(c4 + 1) * 4 + rblk * 2;
        *(uint2*)p = make_uint2(pack_bf16(v0.y, v1.y), pack_bf16(v2.y, v3.y));
        p = lds + bswz(c4 + 2) * 4 + rblk * 2;
        *(uint2*)p = make_uint2(pack_bf16(v0.z, v1.z), pack_bf16(v2.z, v3.z));
        p = lds + bswz(c4 + 3) * 4 + rblk * 2;
        *(uint2*)p = make_uint2(pack_bf16(v0.w, v1.w), pack_bf16(v2.w, v3.w));
    }
    __syncthreads();

    const uint4* __restrict__ ldsq = (const uint4*)lds;

#define CONSUME(d, wv) {                                                       \
        acc0 = fmaf(__uint_as_float(d.x << 16),          wv, acc0);            \
        acc1 = fmaf(__uint_as_float(d.x & 0xFFFF0000u),  wv, acc1);            \
        acc2 = fmaf(__uint_as_float(d.y << 16),          wv, acc2);            \
        acc3 = fmaf(__uint_as_float(d.y & 0xFFFF0000u),  wv, acc3);            \
        acc4 = fmaf(__uint_as_float(d.z << 16),          wv, acc4);            \
        acc5 = fmaf(__uint_as_float(d.z & 0xFFFF0000u),  wv, acc5);            \
        acc6 = fmaf(__uint_as_float(d.w << 16),          wv, acc6);            \
        acc7 = fmaf(__uint_as_float(d.w & 0xFFFF0000u),  wv, acc7);            \
    }

    // Cyclic output mapping -> coalesced stores.
    #pragma unroll 1
    for (int i = 0; i < O_PER_THREAD; ++i) {
        const int o = tid + i * NTHREADS;
        const float bv = bias[o];
        float acc0 = bv, acc1 = bv, acc2 = bv, acc3 = bv;
        float acc4 = bv, acc5 = bv, acc6 = bv, acc7 = bv;

        const int4*   mp = (const int4*)(M + (size_t)o * FAN_IN);
        const float4* wp = (const float4*)(W + (size_t)o * FAN_IN);

        // 3-stage software pipeline over 16 trips of 4 k each:
        //   body c: issue ds-reads for trip c+1 (keeps 8 b128 in flight),
        //           prefetch m/w for trip c+3 (~2 bodies ahead, covers L2 lat),
        //           consume trip c.
        // All ring indices are compile-time after full unroll (no scratch).
        uint4  dbuf[2][4];
        int4   mbuf[4];
        float4 wbuf[4];

        mbuf[0] = mp[0];  wbuf[0] = wp[0];
        mbuf[1] = mp[1];  wbuf[1] = wp[1];
        mbuf[2] = mp[2];  wbuf[2] = wp[2];

        {   // issue trip 0
            const int4 m = mbuf[0];
            dbuf[0][0] = ldsq[bswz(m.x)];
            dbuf[0][1] = ldsq[bswz(m.y)];
            dbuf[0][2] = ldsq[bswz(m.z)];
            dbuf[0][3] = ldsq[bswz(m.w)];
        }

        #pragma unroll
        for (int c = 0; c < FAN_IN / 4; ++c) {        // 16 bodies, fully unrolled
            if (c + 1 < FAN_IN / 4) {                 // issue trip c+1
                const int4 m = mbuf[(c + 1) & 3];
                dbuf[(c + 1) & 1][0] = ldsq[bswz(m.x)];
                dbuf[(c + 1) & 1][1] = ldsq[bswz(m.y)];
                dbuf[(c + 1) & 1][2] = ldsq[bswz(m.z)];
                dbuf[(c + 1) & 1][3] = ldsq[bswz(m.w)];
            }
            if (c + 3 < FAN_IN / 4) {                 // prefetch m/w trip c+3
                mbuf[(c + 3) & 3] = mp[c + 3];
                wbuf[(c + 3) & 3] = wp[c + 3];
            }
            const float4 w = wbuf[c & 3];             // consume trip c
            CONSUME(dbuf[c & 1][0], w.x);
            CONSUME(dbuf[c & 1][1], w.y);
            CONSUME(dbuf[c & 1][2], w.z);
            CONSUME(dbuf[c & 1][3], w.w);
        }

        float* op = out + (size_t)r0 * OUT_DIM + o;
        op[0 * OUT_DIM] = acc0;
        op[1 * OUT_DIM] = acc1;
        op[2 * OUT_DIM] = acc2;
        op[3 * OUT_DIM] = acc3;
        op[4 * OUT_DIM] = acc4;
        op[5 * OUT_DIM] = acc5;
        op[6 * OUT_DIM] = acc6;
        op[7 * OUT_DIM] = acc7;
    }
#undef CONSUME
}

extern "C" void kernel_launch(void* const* d_in, const int* in_sizes, int n_in,
                              void* d_out, int out_size, void* d_ws, size_t ws_size,
                              hipStream_t stream) {
    const float* inp  = (const float*)d_in[0];
    const float* W    = (const float*)d_in[1];
    const int*   M    = (const int*)d_in[2];
    const float* bias = (const float*)d_in[3];
    float* out = (float*)d_out;

    const int n_rows = in_sizes[0] / IN_DIM;          // 4096
    dim3 grid(n_rows / ROWS), block(NTHREADS);
    ffi_sparse_kernel<<<grid, block, 0, stream>>>(inp, W, M, bias, out);
}

// Round 7
// 83.964 us; speedup vs baseline: 2.1948x; 1.5716x over previous
//
#include <hip/hip_runtime.h>

#define IN_DIM   4096
#define OUT_DIM  4096
#define FAN_IN   64
#define ROWS     8
#define NTHREADS 512
#define O_PER_THREAD (OUT_DIM / NTHREADS) // 8
#define MT_BYTES ((size_t)(FAN_IN / 4) * OUT_DIM * 16)  // 1 MB per table

// Bijective 16B-block swizzle: spreads LDS bank-start groups.
__device__ __forceinline__ int bswz(int m) {
    return (m & ~7) | ((m ^ (m >> 3)) & 7);
}

// round-to-nearest f32->bf16, packed pair (a=lo, b=hi)
__device__ __forceinline__ unsigned int pack_bf16(float a, float b) {
    unsigned int ua = __float_as_uint(a);
    ua += 0x7FFFu + ((ua >> 16) & 1u);
    unsigned int ub = __float_as_uint(b);
    ub += 0x7FFFu + ((ub >> 16) & 1u);
    return (ua >> 16) | (ub & 0xFFFF0000u);
}

// Pre-transpose M/W: Mt[kk][o] = int4 of ks 4kk..4kk+3 for output o.
// Consecutive threads share kk, walk o -> writes are contiguous 1KB/wave.
__global__ __launch_bounds__(256)
void transpose_mw(const int* __restrict__ M, const float* __restrict__ W,
                  int4* __restrict__ Mt, float4* __restrict__ Wt)
{
    const int t  = blockIdx.x * 256 + threadIdx.x;  // [0, 65536)
    const int kk = t >> 12;                         // 0..15
    const int o  = t & (OUT_DIM - 1);
    Mt[kk * OUT_DIM + o] = ((const int4*)(M + (size_t)o * FAN_IN))[kk];
    Wt[kk * OUT_DIM + o] = ((const float4*)(W + (size_t)o * FAN_IN))[kk];
}

// 64 KiB LDS -> 2 blocks/CU (LDS-capped, 16 waves/CU). VGPR cap 128.
template <bool TRANSPOSED>
__global__ __launch_bounds__(NTHREADS, 4)
void ffi_sparse_kernel(const float* __restrict__ inp,
                       const float* __restrict__ W,
                       const int*   __restrict__ M,
                       const float* __restrict__ bias,
                       const int4*  __restrict__ Mt,
                       const float4* __restrict__ Wt,
                       float* __restrict__ out)
{
    // [col][8 rows] packed bf16 pairs: one uint4 (16 B) per column. 64 KiB.
    __shared__ unsigned int lds[IN_DIM * ROWS / 2];

    const int tid = threadIdx.x;
    const int r0  = blockIdx.x * ROWS;

    // ---------------- stage: 8 rows x 4096 cols, f32 -> bf16, transpose ----------------
    #pragma unroll
    for (int t = 0; t < (ROWS * IN_DIM / 16) / NTHREADS; ++t) {   // 4 iterations
        const int tile = tid + t * NTHREADS;     // 0..2047
        const int rblk = tile >> 10;             // 0..1
        const int c4   = (tile & 1023) << 2;     // column base
        const float* src = inp + (size_t)(r0 + rblk * 4) * IN_DIM + c4;
        const float4 v0 = *(const float4*)(src);
        const float4 v1 = *(const float4*)(src + IN_DIM);
        const float4 v2 = *(const float4*)(src + 2 * IN_DIM);
        const float4 v3 = *(const float4*)(src + 3 * IN_DIM);

        unsigned int* p;
        p = lds + bswz(c4 + 0) * 4 + rblk * 2;
        *(uint2*)p = make_uint2(pack_bf16(v0.x, v1.x), pack_bf16(v2.x, v3.x));
        p = lds + bswz(c4 + 1) * 4 + rblk * 2;
        *(uint2*)p = make_uint2(pack_bf16(v0.y, v1.y), pack_bf16(v2.y, v3.y));
        p = lds + bswz(c4 + 2) * 4 + rblk * 2;
        *(uint2*)p = make_uint2(pack_bf16(v0.z, v1.z), pack_bf16(v2.z, v3.z));
        p = lds + bswz(c4 + 3) * 4 + rblk * 2;
        *(uint2*)p = make_uint2(pack_bf16(v0.w, v1.w), pack_bf16(v2.w, v3.w));
    }
    __syncthreads();

    const uint4* __restrict__ ldsq = (const uint4*)lds;

#define CONSUME(d, wv) {                                                       \
        acc0 = fmaf(__uint_as_float(d.x << 16),          wv, acc0);            \
        acc1 = fmaf(__uint_as_float(d.x & 0xFFFF0000u),  wv, acc1);            \
        acc2 = fmaf(__uint_as_float(d.y << 16),          wv, acc2);            \
        acc3 = fmaf(__uint_as_float(d.y & 0xFFFF0000u),  wv, acc3);            \
        acc4 = fmaf(__uint_as_float(d.z << 16),          wv, acc4);            \
        acc5 = fmaf(__uint_as_float(d.z & 0xFFFF0000u),  wv, acc5);            \
        acc6 = fmaf(__uint_as_float(d.w << 16),          wv, acc6);            \
        acc7 = fmaf(__uint_as_float(d.w & 0xFFFF0000u),  wv, acc7);            \
    }

    // Cyclic output mapping -> coalesced stores and coalesced Mt/Wt loads.
    #pragma unroll 1
    for (int i = 0; i < O_PER_THREAD; ++i) {
        const int o = tid + i * NTHREADS;
        const float bv = bias[o];
        float acc0 = bv, acc1 = bv, acc2 = bv, acc3 = bv;
        float acc4 = bv, acc5 = bv, acc6 = bv, acc7 = bv;

        const int4*   mp = (const int4*)(M + (size_t)o * FAN_IN);   // fallback
        const float4* wp = (const float4*)(W + (size_t)o * FAN_IN);

        // 3-stage pipeline over 16 trips of 4 k:
        //   issue ds-reads for trip c+1, prefetch m/w for trip c+3, consume trip c.
        uint4  dbuf[2][4];
        int4   mbuf[4];
        float4 wbuf[4];

#define MW_LOAD(dst_m, dst_w, c_) {                                            \
        if (TRANSPOSED) {                                                      \
            dst_m = Mt[(c_) * OUT_DIM + o];    /* 64 lanes x 16B contiguous */ \
            dst_w = Wt[(c_) * OUT_DIM + o];                                    \
        } else {                                                               \
            dst_m = mp[(c_)];                                                  \
            dst_w = wp[(c_)];                                                  \
        }                                                                      \
    }

        MW_LOAD(mbuf[0], wbuf[0], 0);
        MW_LOAD(mbuf[1], wbuf[1], 1);
        MW_LOAD(mbuf[2], wbuf[2], 2);

        {   // issue trip 0
            const int4 m = mbuf[0];
            dbuf[0][0] = ldsq[bswz(m.x)];
            dbuf[0][1] = ldsq[bswz(m.y)];
            dbuf[0][2] = ldsq[bswz(m.z)];
            dbuf[0][3] = ldsq[bswz(m.w)];
        }

        #pragma unroll
        for (int c = 0; c < FAN_IN / 4; ++c) {        // 16 bodies, fully unrolled
            if (c + 1 < FAN_IN / 4) {                 // issue trip c+1
                const int4 m = mbuf[(c + 1) & 3];
                dbuf[(c + 1) & 1][0] = ldsq[bswz(m.x)];
                dbuf[(c + 1) & 1][1] = ldsq[bswz(m.y)];
                dbuf[(c + 1) & 1][2] = ldsq[bswz(m.z)];
                dbuf[(c + 1) & 1][3] = ldsq[bswz(m.w)];
            }
            if (c + 3 < FAN_IN / 4) {                 // prefetch m/w trip c+3
                MW_LOAD(mbuf[(c + 3) & 3], wbuf[(c + 3) & 3], c + 3);
            }
            const float4 w = wbuf[c & 3];             // consume trip c
            CONSUME(dbuf[c & 1][0], w.x);
            CONSUME(dbuf[c & 1][1], w.y);
            CONSUME(dbuf[c & 1][2], w.z);
            CONSUME(dbuf[c & 1][3], w.w);
        }
#undef MW_LOAD

        float* op = out + (size_t)r0 * OUT_DIM + o;
        op[0 * OUT_DIM] = acc0;
        op[1 * OUT_DIM] = acc1;
        op[2 * OUT_DIM] = acc2;
        op[3 * OUT_DIM] = acc3;
        op[4 * OUT_DIM] = acc4;
        op[5 * OUT_DIM] = acc5;
        op[6 * OUT_DIM] = acc6;
        op[7 * OUT_DIM] = acc7;
    }
#undef CONSUME
}

extern "C" void kernel_launch(void* const* d_in, const int* in_sizes, int n_in,
                              void* d_out, int out_size, void* d_ws, size_t ws_size,
                              hipStream_t stream) {
    const float* inp  = (const float*)d_in[0];
    const float* W    = (const float*)d_in[1];
    const int*   M    = (const int*)d_in[2];
    const float* bias = (const float*)d_in[3];
    float* out = (float*)d_out;

    const int n_rows = in_sizes[0] / IN_DIM;          // 4096
    dim3 grid(n_rows / ROWS), block(NTHREADS);

    const bool use_t = ws_size >= 2 * MT_BYTES;
    if (use_t) {
        int4*   Mt = (int4*)d_ws;
        float4* Wt = (float4*)((char*)d_ws + MT_BYTES);
        transpose_mw<<<dim3(OUT_DIM * (FAN_IN / 4) / 256), dim3(256), 0, stream>>>(M, W, Mt, Wt);
        ffi_sparse_kernel<true><<<grid, block, 0, stream>>>(inp, W, M, bias, Mt, Wt, out);
    } else {
        ffi_sparse_kernel<false><<<grid, block, 0, stream>>>(inp, W, M, bias,
                                                             (const int4*)nullptr,
                                                             (const float4*)nullptr, out);
    }
}

// Round 8
// 82.100 us; speedup vs baseline: 2.2446x; 1.0227x over previous
//
#include <hip/hip_runtime.h>

#define IN_DIM   4096
#define OUT_DIM  4096
#define FAN_IN   64
#define ROWS     8
#define NTHREADS 512
#define O_PER_THREAD (OUT_DIM / NTHREADS) // 8
#define MT_BYTES ((size_t)(FAN_IN / 4) * OUT_DIM * 16)  // 1 MB per table

typedef float v2f __attribute__((ext_vector_type(2)));

// Bijective 16B-block swizzle: spreads LDS bank-start groups.
__device__ __forceinline__ int bswz(int m) {
    return (m & ~7) | ((m ^ (m >> 3)) & 7);
}

// round-to-nearest f32->bf16, packed pair (a=lo, b=hi)
__device__ __forceinline__ unsigned int pack_bf16(float a, float b) {
    unsigned int ua = __float_as_uint(a);
    ua += 0x7FFFu + ((ua >> 16) & 1u);
    unsigned int ub = __float_as_uint(b);
    ub += 0x7FFFu + ((ub >> 16) & 1u);
    return (ua >> 16) | (ub & 0xFFFF0000u);
}

// Pre-transpose M/W with PRE-SWIZZLED mask: Mt[kk][o] = bswz applied already,
// so the hot loop does zero address math beyond the load itself.
__global__ __launch_bounds__(256)
void transpose_mw(const int* __restrict__ M, const float* __restrict__ W,
                  int4* __restrict__ Mt, float4* __restrict__ Wt)
{
    const int t  = blockIdx.x * 256 + threadIdx.x;  // [0, 65536)
    const int kk = t >> 12;                         // 0..15
    const int o  = t & (OUT_DIM - 1);
    int4 m = ((const int4*)(M + (size_t)o * FAN_IN))[kk];
    m.x = bswz(m.x); m.y = bswz(m.y); m.z = bswz(m.z); m.w = bswz(m.w);
    Mt[kk * OUT_DIM + o] = m;
    Wt[kk * OUT_DIM + o] = ((const float4*)(W + (size_t)o * FAN_IN))[kk];
}

// 64 KiB LDS -> 2 blocks/CU (LDS-capped, 16 waves/CU). VGPR cap 128.
template <bool TRANSPOSED>
__global__ __launch_bounds__(NTHREADS, 4)
void ffi_sparse_kernel(const float* __restrict__ inp,
                       const float* __restrict__ W,
                       const int*   __restrict__ M,
                       const float* __restrict__ bias,
                       const int4*  __restrict__ Mt,
                       const float4* __restrict__ Wt,
                       float* __restrict__ out)
{
    // [col][8 rows] packed bf16 pairs: one uint4 (16 B) per column. 64 KiB.
    __shared__ unsigned int lds[IN_DIM * ROWS / 2];

    const int tid = threadIdx.x;
    const int r0  = blockIdx.x * ROWS;

    // ---------------- stage: 8 rows x 4096 cols, f32 -> bf16, transpose ----------------
    #pragma unroll
    for (int t = 0; t < (ROWS * IN_DIM / 16) / NTHREADS; ++t) {   // 4 iterations
        const int tile = tid + t * NTHREADS;     // 0..2047
        const int rblk = tile >> 10;             // 0..1
        const int c4   = (tile & 1023) << 2;     // column base
        const float* src = inp + (size_t)(r0 + rblk * 4) * IN_DIM + c4;
        const float4 v0 = *(const float4*)(src);
        const float4 v1 = *(const float4*)(src + IN_DIM);
        const float4 v2 = *(const float4*)(src + 2 * IN_DIM);
        const float4 v3 = *(const float4*)(src + 3 * IN_DIM);

        unsigned int* p;
        p = lds + bswz(c4 + 0) * 4 + rblk * 2;
        *(uint2*)p = make_uint2(pack_bf16(v0.x, v1.x), pack_bf16(v2.x, v3.x));
        p = lds + bswz(c4 + 1) * 4 + rblk * 2;
        *(uint2*)p = make_uint2(pack_bf16(v0.y, v1.y), pack_bf16(v2.y, v3.y));
        p = lds + bswz(c4 + 2) * 4 + rblk * 2;
        *(uint2*)p = make_uint2(pack_bf16(v0.z, v1.z), pack_bf16(v2.z, v3.z));
        p = lds + bswz(c4 + 3) * 4 + rblk * 2;
        *(uint2*)p = make_uint2(pack_bf16(v0.w, v1.w), pack_bf16(v2.w, v3.w));
    }
    __syncthreads();

    const uint4* __restrict__ ldsq = (const uint4*)lds;

    // Packed-pair consume: 4x v_pk_fma_f32 + 8 unpack per (o,k).
    // acc pairs: accP = rows (2P, 2P+1).
#define CONSUME(d, wv) {                                                       \
        const v2f w2 = {wv, wv};                                               \
        v2f x;                                                                 \
        x.x = __uint_as_float(d.x << 16);                                      \
        x.y = __uint_as_float(d.x & 0xFFFF0000u);                              \
        accA = __builtin_elementwise_fma(x, w2, accA);                         \
        x.x = __uint_as_float(d.y << 16);                                      \
        x.y = __uint_as_float(d.y & 0xFFFF0000u);                              \
        accB = __builtin_elementwise_fma(x, w2, accB);                         \
        x.x = __uint_as_float(d.z << 16);                                      \
        x.y = __uint_as_float(d.z & 0xFFFF0000u);                              \
        accC = __builtin_elementwise_fma(x, w2, accC);                         \
        x.x = __uint_as_float(d.w << 16);                                      \
        x.y = __uint_as_float(d.w & 0xFFFF0000u);                              \
        accD = __builtin_elementwise_fma(x, w2, accD);                         \
    }

    // Cyclic output mapping -> coalesced stores and coalesced Mt/Wt loads.
    #pragma unroll 1
    for (int i = 0; i < O_PER_THREAD; ++i) {
        const int o = tid + i * NTHREADS;
        const float bv = bias[o];
        v2f accA = {bv, bv}, accB = {bv, bv}, accC = {bv, bv}, accD = {bv, bv};

        const int4*   mp = (const int4*)(M + (size_t)o * FAN_IN);   // fallback
        const float4* wp = (const float4*)(W + (size_t)o * FAN_IN);

        // 3-stage pipeline over 16 trips of 4 k:
        //   issue ds-reads for trip c+1, prefetch m/w for trip c+3, consume trip c.
        uint4  dbuf[2][4];
        int4   mbuf[4];
        float4 wbuf[4];

#define MW_LOAD(dst_m, dst_w, c_) {                                            \
        if (TRANSPOSED) {                                                      \
            dst_m = Mt[(c_) * OUT_DIM + o];    /* pre-swizzled, contiguous */  \
            dst_w = Wt[(c_) * OUT_DIM + o];                                    \
        } else {                                                               \
            int4 mr = mp[(c_)];                                                \
            mr.x = bswz(mr.x); mr.y = bswz(mr.y);                              \
            mr.z = bswz(mr.z); mr.w = bswz(mr.w);                              \
            dst_m = mr;                                                        \
            dst_w = wp[(c_)];                                                  \
        }                                                                      \
    }

        MW_LOAD(mbuf[0], wbuf[0], 0);
        MW_LOAD(mbuf[1], wbuf[1], 1);
        MW_LOAD(mbuf[2], wbuf[2], 2);

        {   // issue trip 0
            const int4 m = mbuf[0];
            dbuf[0][0] = ldsq[m.x];
            dbuf[0][1] = ldsq[m.y];
            dbuf[0][2] = ldsq[m.z];
            dbuf[0][3] = ldsq[m.w];
        }

        #pragma unroll
        for (int c = 0; c < FAN_IN / 4; ++c) {        // 16 bodies, fully unrolled
            if (c + 1 < FAN_IN / 4) {                 // issue trip c+1
                const int4 m = mbuf[(c + 1) & 3];
                dbuf[(c + 1) & 1][0] = ldsq[m.x];
                dbuf[(c + 1) & 1][1] = ldsq[m.y];
                dbuf[(c + 1) & 1][2] = ldsq[m.z];
                dbuf[(c + 1) & 1][3] = ldsq[m.w];
            }
            if (c + 3 < FAN_IN / 4) {                 // prefetch m/w trip c+3
                MW_LOAD(mbuf[(c + 3) & 3], wbuf[(c + 3) & 3], c + 3);
            }
            const float4 w = wbuf[c & 3];             // consume trip c
            CONSUME(dbuf[c & 1][0], w.x);
            CONSUME(dbuf[c & 1][1], w.y);
            CONSUME(dbuf[c & 1][2], w.z);
            CONSUME(dbuf[c & 1][3], w.w);
        }
#undef MW_LOAD

        float* op = out + (size_t)r0 * OUT_DIM + o;
        op[0 * OUT_DIM] = accA.x;
        op[1 * OUT_DIM] = accA.y;
        op[2 * OUT_DIM] = accB.x;
        op[3 * OUT_DIM] = accB.y;
        op[4 * OUT_DIM] = accC.x;
        op[5 * OUT_DIM] = accC.y;
        op[6 * OUT_DIM] = accD.x;
        op[7 * OUT_DIM] = accD.y;
    }
#undef CONSUME
}

extern "C" void kernel_launch(void* const* d_in, const int* in_sizes, int n_in,
                              void* d_out, int out_size, void* d_ws, size_t ws_size,
                              hipStream_t stream) {
    const float* inp  = (const float*)d_in[0];
    const float* W    = (const float*)d_in[1];
    const int*   M    = (const int*)d_in[2];
    const float* bias = (const float*)d_in[3];
    float* out = (float*)d_out;

    const int n_rows = in_sizes[0] / IN_DIM;          // 4096
    dim3 grid(n_rows / ROWS), block(NTHREADS);

    const bool use_t = ws_size >= 2 * MT_BYTES;
    if (use_t) {
        int4*   Mt = (int4*)d_ws;
        float4* Wt = (float4*)((char*)d_ws + MT_BYTES);
        transpose_mw<<<dim3(OUT_DIM * (FAN_IN / 4) / 256), dim3(256), 0, stream>>>(M, W, Mt, Wt);
        ffi_sparse_kernel<true><<<grid, block, 0, stream>>>(inp, W, M, bias, Mt, Wt, out);
    } else {
        ffi_sparse_kernel<false><<<grid, block, 0, stream>>>(inp, W, M, bias,
                                                             (const int4*)nullptr,
                                                             (const float4*)nullptr, out);
    }
}